// Round 1
// baseline (720.321 us; speedup 1.0000x reference)
//
#include <hip/hip_runtime.h>

#define SB 16
#define SN 2048
#define SD 128
#define NM 2049
#define SZ (SB*SN*SD)   // 4194304 elements per (B,N,D) tensor

typedef __bf16 bf16x8 __attribute__((ext_vector_type(8)));
typedef float f32x4 __attribute__((ext_vector_type(4)));

// float -> bf16 round-to-nearest-even (inputs are finite; no NaN guard needed)
__device__ __forceinline__ unsigned short f2b(float f){
  union { float f; unsigned int u; } v; v.f = f;
  unsigned int r = v.u + 0x7fffu + ((v.u >> 16) & 1u);
  return (unsigned short)(r >> 16);
}

__device__ __forceinline__ void async16(const void* g, void* l){
#if defined(__has_builtin) && __has_builtin(__builtin_amdgcn_global_load_lds)
  __builtin_amdgcn_global_load_lds(
      (__attribute__((address_space(1))) void*)(g),
      (__attribute__((address_space(3))) void*)(l), 16, 0, 0);
#else
  *(uint4*)(l) = *(const uint4*)(g);
#endif
}

// ---- transpose + cvt the 4 weight matrices: Wt[n*128+k] = bf16(W[k*128+n]) ----
__global__ __launch_bounds__(256) void prep_w_kernel(
    const float* __restrict__ Wq, const float* __restrict__ Wk,
    const float* __restrict__ Wv, const float* __restrict__ Wo,
    unsigned short* __restrict__ out)
{
  int widx = blockIdx.x >> 4;           // matrix 0..3
  int kg   = blockIdx.x & 15;           // 8 rows per block
  const float* W = (widx==0)?Wq:(widx==1)?Wk:(widx==2)?Wv:Wo;
  unsigned short* O = out + widx*16384;
  int t = threadIdx.x;
  int k = kg*8 + (t>>5);
  int n = (t&31)*4;
  float4 v = *reinterpret_cast<const float4*>(W + k*SD + n);
  O[(n+0)*SD + k] = f2b(v.x);
  O[(n+1)*SD + k] = f2b(v.y);
  O[(n+2)*SD + k] = f2b(v.z);
  O[(n+3)*SD + k] = f2b(v.w);
}

// ---- generic projection: fp32 X (rows x 128) @ Wt + bias -> bf16 out ----
__global__ __launch_bounds__(256) void proj_kernel(
    const float* __restrict__ X, const unsigned short* __restrict__ Wt,
    const float* __restrict__ bias, unsigned short* __restrict__ out)
{
  int tid = threadIdx.x;
  int w = tid>>6, ln = tid&63, g = ln>>4, lm = ln&15;
  int r0 = blockIdx.x*64;
  const float* xr = X + (size_t)(r0 + w*16 + lm)*SD;
  bf16x8 af[4];
  for (int ks=0;ks<4;ks++){
    float4 x0 = *reinterpret_cast<const float4*>(xr + ks*32 + g*8);
    float4 x1 = *reinterpret_cast<const float4*>(xr + ks*32 + g*8 + 4);
    union { bf16x8 v; unsigned short s[8]; } u;
    u.s[0]=f2b(x0.x); u.s[1]=f2b(x0.y); u.s[2]=f2b(x0.z); u.s[3]=f2b(x0.w);
    u.s[4]=f2b(x1.x); u.s[5]=f2b(x1.y); u.s[6]=f2b(x1.z); u.s[7]=f2b(x1.w);
    af[ks]=u.v;
  }
  int rbase = r0 + w*16 + 4*g;
  for (int d=0; d<8; d++){
    f32x4 acc = {0.f,0.f,0.f,0.f};
    for (int ks=0;ks<4;ks++){
      bf16x8 wf = *reinterpret_cast<const bf16x8*>(Wt + (d*16+lm)*SD + ks*32 + g*8);
      acc = __builtin_amdgcn_mfma_f32_16x16x32_bf16(af[ks], wf, acc, 0,0,0);
    }
    float bv = bias[d*16+lm];
    for (int r=0;r<4;r++)
      out[(size_t)(rbase+r)*SD + d*16 + lm] = f2b(acc[r]+bv);
  }
}

// ---- v = k_bf16 @ Wv + bv, stored transposed: vt[b][d][n] ----
__global__ __launch_bounds__(256) void vproj_kernel(
    const unsigned short* __restrict__ kb, const unsigned short* __restrict__ Wt,
    const float* __restrict__ bias, unsigned short* __restrict__ vt)
{
  __shared__ unsigned short vT[SD*72];   // [col(d)][row(n-local)], stride 72 keeps 16B align
  int tid=threadIdx.x;
  int w=tid>>6, ln=tid&63, g=ln>>4, lm=ln&15;
  int b = blockIdx.x >> 5, nt = blockIdx.x & 31;
  int n0 = nt*64;
  const unsigned short* kr = kb + ((size_t)b*SN + n0 + w*16 + lm)*SD;
  bf16x8 af[4];
  for (int ks=0;ks<4;ks++)
    af[ks] = *reinterpret_cast<const bf16x8*>(kr + ks*32 + g*8);
  for (int d=0;d<8;d++){
    f32x4 acc = {0.f,0.f,0.f,0.f};
    for (int ks=0;ks<4;ks++){
      bf16x8 wf = *reinterpret_cast<const bf16x8*>(Wt + (d*16+lm)*SD + ks*32 + g*8);
      acc = __builtin_amdgcn_mfma_f32_16x16x32_bf16(af[ks], wf, acc, 0,0,0);
    }
    float bv = bias[d*16+lm];
    int col = d*16+lm;
    ushort4 pk;
    pk.x = f2b(acc[0]+bv); pk.y = f2b(acc[1]+bv);
    pk.z = f2b(acc[2]+bv); pk.w = f2b(acc[3]+bv);
    *reinterpret_cast<ushort4*>(&vT[col*72 + w*16 + 4*g]) = pk;  // 4 consecutive rows
  }
  __syncthreads();
  // coalesced write-out: vt[b][d][n0 .. n0+63]
  int d = tid>>1, half = tid&1;
  const uint4* src = reinterpret_cast<const uint4*>(&vT[d*72 + half*32]);
  uint4* dst = reinterpret_cast<uint4*>(vt + (size_t)b*SD*SN + (size_t)d*SN + n0 + half*32);
  for (int i=0;i<4;i++) dst[i] = src[i];
}

// ---- flash attention: S=QK^T/sqrt(D), mask(m->-inf), online softmax, O=PV ----
__global__ __launch_bounds__(256) void flash_kernel(
    const unsigned short* __restrict__ qb, const unsigned short* __restrict__ kb,
    const unsigned short* __restrict__ vt, const int* __restrict__ mask,
    float* __restrict__ attn)
{
  __shared__ unsigned short ldsK[64*SD];    // K tile  [key64][d128]
  __shared__ unsigned short ldsV[SD*64];    // Vt tile [d128][key64]
  __shared__ unsigned short ldsP[4*16*72];  // per-wave P strip [16 rows][64 keys], stride 72

  int tid=threadIdx.x;
  int w=tid>>6, ln=tid&63, g=ln>>4, lm=ln&15;
  int b = blockIdx.x >> 5, qt = blockIdx.x & 31;
  int q0 = qt*64;

  const unsigned short* Qb = qb + (size_t)b*SN*SD;
  const unsigned short* Kb = kb + (size_t)b*SN*SD;
  const unsigned short* Vb = vt + (size_t)b*SD*SN;
  const int* Mb = mask + (size_t)b*NM*NM;

  bf16x8 qf[4];
  {
    const unsigned short* qr = Qb + (size_t)(q0 + w*16 + lm)*SD;
    for (int ks=0;ks<4;ks++)
      qf[ks] = *reinterpret_cast<const bf16x8*>(qr + ks*32 + g*8);
  }

  float mrow[4], lrow[4], al[4];
  f32x4 acc[8];
  for (int r=0;r<4;r++){ mrow[r]=-INFINITY; lrow[r]=0.f; }
  for (int d=0;d<8;d++){ f32x4 z={0.f,0.f,0.f,0.f}; acc[d]=z; }

  unsigned short* pw = &ldsP[w*16*72];
  const float sc = 0.08838834764831845f;  // 1/sqrt(128)

  for (int kt=0; kt<32; kt++){
    int k0 = kt*64;
    {
      const char* gK = (const char*)(Kb + (size_t)k0*SD);
      const char* gVbase = (const char*)Vb + (size_t)k0*2;
      char* lK = (char*)ldsK;
      char* lV = (char*)ldsV;
      for (int c=0;c<4;c++){          // K tile: contiguous 16KB
        int off = (c*256 + tid)*16;
        async16(gK + off, lK + off);
      }
      for (int c=0;c<4;c++){          // Vt tile: 128 rows of 128B, global stride SN*2
        int off = (c*256 + tid)*16;
        int dd = off >> 7;
        int colb = off & 127;
        async16(gVbase + (size_t)dd*(SN*2) + colb, lV + off);
      }
    }
    __syncthreads();

    // S = Q K^T (wave strip: 16 q-rows x 64 keys)
    f32x4 s[4];
    for (int ct=0;ct<4;ct++){
      f32x4 z = {0.f,0.f,0.f,0.f};
      for (int ks=0;ks<4;ks++){
        bf16x8 kf = *reinterpret_cast<const bf16x8*>(&ldsK[(ct*16+lm)*SD + ks*32 + g*8]);
        z = __builtin_amdgcn_mfma_f32_16x16x32_bf16(qf[ks], kf, z, 0,0,0);
      }
      s[ct]=z;
    }

    // scale + inverted mask (mask true -> -inf); mask[b, 1+qi, 1+ki]
    int qr1 = 1 + q0 + w*16 + 4*g;
    for (int ct=0;ct<4;ct++){
      int kc1 = 1 + k0 + ct*16 + lm;
      const int* mp = Mb + (size_t)qr1*NM + kc1;
      for (int r=0;r<4;r++){
        int mk = mp[(size_t)r*NM];
        float sv = s[ct][r]*sc;
        s[ct][r] = mk ? -INFINITY : sv;
      }
    }

    // online softmax, rows 4g+r, cols spread over ct (in-lane) x lm (16 lanes)
    for (int r=0;r<4;r++){
      float v = fmaxf(fmaxf(s[0][r],s[1][r]), fmaxf(s[2][r],s[3][r]));
      v = fmaxf(v, __shfl_xor(v,1,16));
      v = fmaxf(v, __shfl_xor(v,2,16));
      v = fmaxf(v, __shfl_xor(v,4,16));
      v = fmaxf(v, __shfl_xor(v,8,16));
      float mn = fmaxf(mrow[r], v);
      bool dead = (mn == -INFINITY);      // fully-masked so far -> output 0 (NaN->0 semantics)
      float a = dead ? 1.f : __expf(mrow[r]-mn);
      float rsum = 0.f;
      for (int ct=0;ct<4;ct++){
        float p = dead ? 0.f : __expf(s[ct][r]-mn);
        s[ct][r]=p; rsum += p;
      }
      rsum += __shfl_xor(rsum,1,16);
      rsum += __shfl_xor(rsum,2,16);
      rsum += __shfl_xor(rsum,4,16);
      rsum += __shfl_xor(rsum,8,16);
      lrow[r] = lrow[r]*a + rsum;
      mrow[r] = mn;
      al[r] = a;
    }

    for (int d=0;d<8;d++)
      for (int r=0;r<4;r++)
        acc[d][r] *= al[r];

    // P: C-layout -> LDS (per-wave private strip; in-wave lgkmcnt ordering suffices)
    for (int ct=0;ct<4;ct++){
      int col = ct*16+lm;
      for (int r=0;r<4;r++)
        pw[(4*g+r)*72 + col] = f2b(s[ct][r]);
    }
    bf16x8 pa0 = *reinterpret_cast<const bf16x8*>(&pw[lm*72 + g*8]);
    bf16x8 pa1 = *reinterpret_cast<const bf16x8*>(&pw[lm*72 + 32 + g*8]);

    // O += P V  (B-frag from Vt: key contiguous at fixed d)
    for (int d=0;d<8;d++){
      bf16x8 v0 = *reinterpret_cast<const bf16x8*>(&ldsV[(d*16+lm)*64 + g*8]);
      acc[d] = __builtin_amdgcn_mfma_f32_16x16x32_bf16(pa0, v0, acc[d], 0,0,0);
      bf16x8 v1 = *reinterpret_cast<const bf16x8*>(&ldsV[(d*16+lm)*64 + 32 + g*8]);
      acc[d] = __builtin_amdgcn_mfma_f32_16x16x32_bf16(pa1, v1, acc[d], 0,0,0);
    }
    __syncthreads();   // protect ldsK/ldsV before next iteration's staging
  }

  float* Ob = attn + (size_t)b*SN*SD;
  int rbase = q0 + w*16 + 4*g;
  for (int r=0;r<4;r++){
    float inv = (lrow[r] > 0.f) ? (1.f/lrow[r]) : 0.f;
    for (int d=0;d<8;d++)
      Ob[(size_t)(rbase+r)*SD + d*16+lm] = acc[d][r]*inv;
  }
}

// ---- final projection: fp32 attn @ Wo + bo -> fp32 out ----
__global__ __launch_bounds__(256) void oproj_kernel(
    const float* __restrict__ X, const unsigned short* __restrict__ Wt,
    const float* __restrict__ bias, float* __restrict__ out)
{
  int tid = threadIdx.x;
  int w = tid>>6, ln = tid&63, g = ln>>4, lm = ln&15;
  int r0 = blockIdx.x*64;
  const float* xr = X + (size_t)(r0 + w*16 + lm)*SD;
  bf16x8 af[4];
  for (int ks=0;ks<4;ks++){
    float4 x0 = *reinterpret_cast<const float4*>(xr + ks*32 + g*8);
    float4 x1 = *reinterpret_cast<const float4*>(xr + ks*32 + g*8 + 4);
    union { bf16x8 v; unsigned short s[8]; } u;
    u.s[0]=f2b(x0.x); u.s[1]=f2b(x0.y); u.s[2]=f2b(x0.z); u.s[3]=f2b(x0.w);
    u.s[4]=f2b(x1.x); u.s[5]=f2b(x1.y); u.s[6]=f2b(x1.z); u.s[7]=f2b(x1.w);
    af[ks]=u.v;
  }
  int rbase = r0 + w*16 + 4*g;
  for (int d=0; d<8; d++){
    f32x4 acc = {0.f,0.f,0.f,0.f};
    for (int ks=0;ks<4;ks++){
      bf16x8 wf = *reinterpret_cast<const bf16x8*>(Wt + (d*16+lm)*SD + ks*32 + g*8);
      acc = __builtin_amdgcn_mfma_f32_16x16x32_bf16(af[ks], wf, acc, 0,0,0);
    }
    float bv = bias[d*16+lm];
    for (int r=0;r<4;r++)
      out[(size_t)(rbase+r)*SD + d*16 + lm] = acc[r]+bv;
  }
}

extern "C" void kernel_launch(void* const* d_in, const int* in_sizes, int n_in,
                              void* d_out, int out_size, void* d_ws, size_t ws_size,
                              hipStream_t stream)
{
  const float* query = (const float*)d_in[0];
  const float* key   = (const float*)d_in[1];
  const int*   mask  = (const int*)d_in[2];
  const float* Wq = (const float*)d_in[3];
  const float* bq = (const float*)d_in[4];
  const float* Wk = (const float*)d_in[5];
  const float* bk = (const float*)d_in[6];
  const float* Wv = (const float*)d_in[7];
  const float* bv = (const float*)d_in[8];
  const float* Wo = (const float*)d_in[9];
  const float* bo = (const float*)d_in[10];
  float* out = (float*)d_out;

  // workspace layout (~40.1 MB total)
  unsigned short* qb = (unsigned short*)d_ws;        // bf16 q, row-major
  unsigned short* kb = qb + SZ;                      // bf16 k, row-major
  unsigned short* vt = kb + SZ;                      // bf16 v transposed [b][d][n]
  float* attn        = (float*)(vt + SZ);            // fp32 attention output
  unsigned short* wts = (unsigned short*)(attn + SZ);// 4x transposed bf16 weights

  prep_w_kernel<<<64,256,0,stream>>>(Wq,Wk,Wv,Wo,wts);
  proj_kernel  <<<512,256,0,stream>>>(query, wts,        bq, qb);
  proj_kernel  <<<512,256,0,stream>>>(key,   wts+16384,  bk, kb);
  vproj_kernel <<<512,256,0,stream>>>(kb,    wts+32768,  bv, vt);
  flash_kernel <<<512,256,0,stream>>>(qb, kb, vt, mask, attn);
  oproj_kernel <<<512,256,0,stream>>>(attn,  wts+49152,  bo, out);
}

// Round 3
// 662.729 us; speedup vs baseline: 1.0869x; 1.0869x over previous
//
#include <hip/hip_runtime.h>

#define SB 16
#define SN 2048
#define SD 128
#define NM 2049
#define SZ (SB*SN*SD)   // 4194304 elements per (B,N,D) tensor

#define KP 136   // ldsK row stride (ushorts): 272B/row -> bank shift 4/row, conflict-free b128 reads
#define VP 72    // ldsV row stride (ushorts): 144B/row -> bank shift 4/row, conflict-free b128 reads

typedef __bf16 bf16x8 __attribute__((ext_vector_type(8)));
typedef float f32x4 __attribute__((ext_vector_type(4)));

// float -> bf16 round-to-nearest-even (inputs are finite; no NaN guard needed)
__device__ __forceinline__ unsigned short f2b(float f){
  union { float f; unsigned int u; } v; v.f = f;
  unsigned int r = v.u + 0x7fffu + ((v.u >> 16) & 1u);
  return (unsigned short)(r >> 16);
}

// ---- transpose + cvt the 4 weight matrices: Wt[n*128+k] = bf16(W[k*128+n]) ----
__global__ __launch_bounds__(256) void prep_w_kernel(
    const float* __restrict__ Wq, const float* __restrict__ Wk,
    const float* __restrict__ Wv, const float* __restrict__ Wo,
    unsigned short* __restrict__ out)
{
  int widx = blockIdx.x >> 4;           // matrix 0..3
  int kg   = blockIdx.x & 15;           // 8 rows per block
  const float* W = (widx==0)?Wq:(widx==1)?Wk:(widx==2)?Wv:Wo;
  unsigned short* O = out + widx*16384;
  int t = threadIdx.x;
  int k = kg*8 + (t>>5);
  int n = (t&31)*4;
  float4 v = *reinterpret_cast<const float4*>(W + k*SD + n);
  O[(n+0)*SD + k] = f2b(v.x);
  O[(n+1)*SD + k] = f2b(v.y);
  O[(n+2)*SD + k] = f2b(v.z);
  O[(n+3)*SD + k] = f2b(v.w);
}

// ---- projection: fp32 X (16 rows x 128) @ Wt, *scale, + bias -> bf16 out ----
// 2048 blocks x 4 waves; wave w computes d-groups {2w, 2w+1} for the block's 16 rows.
__global__ __launch_bounds__(256) void proj_kernel(
    const float* __restrict__ X, const unsigned short* __restrict__ Wt,
    const float* __restrict__ bias, float scale, unsigned short* __restrict__ out)
{
  int tid = threadIdx.x;
  int w = tid>>6, ln = tid&63, g = ln>>4, lm = ln&15;
  int r0 = blockIdx.x*16;
  const float* xr = X + (size_t)(r0 + lm)*SD;
  bf16x8 af[4];
  for (int ks=0;ks<4;ks++){
    float4 x0 = *reinterpret_cast<const float4*>(xr + ks*32 + g*8);
    float4 x1 = *reinterpret_cast<const float4*>(xr + ks*32 + g*8 + 4);
    union { bf16x8 v; unsigned short s[8]; } u;
    u.s[0]=f2b(x0.x); u.s[1]=f2b(x0.y); u.s[2]=f2b(x0.z); u.s[3]=f2b(x0.w);
    u.s[4]=f2b(x1.x); u.s[5]=f2b(x1.y); u.s[6]=f2b(x1.z); u.s[7]=f2b(x1.w);
    af[ks]=u.v;
  }
  for (int dg=0; dg<2; dg++){
    int d = w*2 + dg;
    f32x4 acc = {0.f,0.f,0.f,0.f};
    for (int ks=0;ks<4;ks++){
      bf16x8 wf = *reinterpret_cast<const bf16x8*>(Wt + (d*16+lm)*SD + ks*32 + g*8);
      acc = __builtin_amdgcn_mfma_f32_16x16x32_bf16(af[ks], wf, acc, 0,0,0);
    }
    float bv = bias[d*16+lm];
    for (int r=0;r<4;r++)
      out[(size_t)(r0+4*g+r)*SD + d*16 + lm] = f2b((acc[r]+bv)*scale);
  }
}

// ---- v = k_bf16 @ Wv + bv, stored transposed: vt[b][d][n] ----
__global__ __launch_bounds__(256) void vproj_kernel(
    const unsigned short* __restrict__ kb, const unsigned short* __restrict__ Wt,
    const float* __restrict__ bias, unsigned short* __restrict__ vt)
{
  __shared__ unsigned short vT[SD*72];   // [col(d)][row(n-local)], stride 72 keeps 16B align
  int tid=threadIdx.x;
  int w=tid>>6, ln=tid&63, g=ln>>4, lm=ln&15;
  int b = blockIdx.x >> 5, nt = blockIdx.x & 31;
  int n0 = nt*64;
  const unsigned short* kr = kb + ((size_t)b*SN + n0 + w*16 + lm)*SD;
  bf16x8 af[4];
  for (int ks=0;ks<4;ks++)
    af[ks] = *reinterpret_cast<const bf16x8*>(kr + ks*32 + g*8);
  for (int d=0;d<8;d++){
    f32x4 acc = {0.f,0.f,0.f,0.f};
    for (int ks=0;ks<4;ks++){
      bf16x8 wf = *reinterpret_cast<const bf16x8*>(Wt + (d*16+lm)*SD + ks*32 + g*8);
      acc = __builtin_amdgcn_mfma_f32_16x16x32_bf16(af[ks], wf, acc, 0,0,0);
    }
    float bv = bias[d*16+lm];
    int col = d*16+lm;
    ushort4 pk;
    pk.x = f2b(acc[0]+bv); pk.y = f2b(acc[1]+bv);
    pk.z = f2b(acc[2]+bv); pk.w = f2b(acc[3]+bv);
    *reinterpret_cast<ushort4*>(&vT[col*72 + w*16 + 4*g]) = pk;  // 4 consecutive rows
  }
  __syncthreads();
  // coalesced write-out: vt[b][d][n0 .. n0+63]
  int d = tid>>1, half = tid&1;
  const uint4* src = reinterpret_cast<const uint4*>(&vT[d*72 + half*32]);
  uint4* dst = reinterpret_cast<uint4*>(vt + (size_t)b*SD*SN + (size_t)d*SN + n0 + half*32);
  for (int i=0;i<4;i++) dst[i] = src[i];
}

// ---- flash attention, register-prefetch pipeline ----
// q is pre-scaled by 1/sqrt(D). Per iter: store prefetched K/V regs -> padded LDS,
// prefetch tile kt+1 (K,V,mask) into regs, then QK -> mask -> online softmax -> PV.
__global__ __launch_bounds__(256) void flash_kernel(
    const unsigned short* __restrict__ qb, const unsigned short* __restrict__ kb,
    const unsigned short* __restrict__ vt, const int* __restrict__ mask,
    float* __restrict__ attn)
{
  __shared__ unsigned short ldsK[64*KP];    // K tile  [key64][d128], padded
  __shared__ unsigned short ldsV[SD*VP];    // Vt tile [d128][key64], padded
  __shared__ unsigned short ldsP[4*16*72];  // per-wave P strip [16 rows][64 keys]

  int tid=threadIdx.x;
  int w=tid>>6, ln=tid&63, g=ln>>4, lm=ln&15;
  int b = blockIdx.x >> 5, qt = blockIdx.x & 31;
  int q0 = qt*64;

  const unsigned short* Qb = qb + (size_t)b*SN*SD;
  const unsigned short* Kb = kb + (size_t)b*SN*SD;
  const unsigned short* Vb = vt + (size_t)b*SD*SN;
  const int* Mb = mask + (size_t)b*NM*NM;

  bf16x8 qf[4];
  {
    const unsigned short* qr = Qb + (size_t)(q0 + w*16 + lm)*SD;
    for (int ks=0;ks<4;ks++)
      qf[ks] = *reinterpret_cast<const bf16x8*>(qr + ks*32 + g*8);
  }

  float mrow[4], lrow[4], al[4];
  f32x4 acc[8];
  for (int r=0;r<4;r++){ mrow[r]=-INFINITY; lrow[r]=0.f; }
  for (int d=0;d<8;d++){ f32x4 z={0.f,0.f,0.f,0.f}; acc[d]=z; }

  unsigned short* pw = &ldsP[w*16*72];
  int qr1 = 1 + q0 + w*16 + 4*g;

  // ---- prefetch tile 0 into regs ----
  uint4 kreg[4], vreg[4];
  int mreg[16];
  {
    const char* gK = (const char*)Kb;
    const char* gV = (const char*)Vb;
    for (int c=0;c<4;c++)
      kreg[c] = *reinterpret_cast<const uint4*>(gK + (c*256+tid)*16);
    for (int c=0;c<4;c++){
      int off=(c*256+tid)*16; int dd=off>>7, colb=off&127;
      vreg[c] = *reinterpret_cast<const uint4*>(gV + (size_t)dd*(SN*2) + colb);
    }
    const int* mp = Mb + (size_t)qr1*NM + 1 + lm;
    for (int ct=0;ct<4;ct++)
      for (int r=0;r<4;r++)
        mreg[ct*4+r] = mp[(size_t)r*NM + ct*16];
  }

  for (int kt=0; kt<32; kt++){
    __syncthreads();   // previous iteration's LDS reads complete
    // store staged K tile (padded rows)
    for (int c=0;c<4;c++){
      int idx=c*256+tid; int row=idx>>4, col=(idx&15)*8;
      *reinterpret_cast<uint4*>(&ldsK[row*KP+col]) = kreg[c];
    }
    // store staged V tile (padded rows)
    for (int c=0;c<4;c++){
      int off=(c*256+tid)*16; int dd=off>>7, col=(off&127)>>1;
      *reinterpret_cast<uint4*>(&ldsV[dd*VP+col]) = vreg[c];
    }
    int mcur[16];
    for (int i=0;i<16;i++) mcur[i]=mreg[i];
    __syncthreads();

    // ---- prefetch tile kt+1 (clamped at the end; redundant reload is L2-hot) ----
    {
      int k0n = (kt<31) ? (kt+1)*64 : kt*64;
      const char* gK = (const char*)(Kb + (size_t)k0n*SD);
      const char* gV = (const char*)Vb + (size_t)k0n*2;
      for (int c=0;c<4;c++)
        kreg[c] = *reinterpret_cast<const uint4*>(gK + (c*256+tid)*16);
      for (int c=0;c<4;c++){
        int off=(c*256+tid)*16; int dd=off>>7, colb=off&127;
        vreg[c] = *reinterpret_cast<const uint4*>(gV + (size_t)dd*(SN*2) + colb);
      }
      const int* mp = Mb + (size_t)qr1*NM + 1 + k0n + lm;
      for (int ct=0;ct<4;ct++)
        for (int r=0;r<4;r++)
          mreg[ct*4+r] = mp[(size_t)r*NM + ct*16];
    }

    // ---- S = Q K^T (wave strip: 16 q-rows x 64 keys) ----
    f32x4 s[4];
    for (int ct=0;ct<4;ct++){
      f32x4 z = {0.f,0.f,0.f,0.f};
      for (int ks=0;ks<4;ks++){
        bf16x8 kf = *reinterpret_cast<const bf16x8*>(&ldsK[(ct*16+lm)*KP + ks*32 + g*8]);
        z = __builtin_amdgcn_mfma_f32_16x16x32_bf16(qf[ks], kf, z, 0,0,0);
      }
      s[ct]=z;
    }

    // inverted mask (mask true -> -inf); q pre-scaled so no multiply here
    for (int ct=0;ct<4;ct++)
      for (int r=0;r<4;r++)
        s[ct][r] = mcur[ct*4+r] ? -INFINITY : s[ct][r];

    // online softmax, rows 4g+r, cols spread over ct (in-lane) x lm (16 lanes)
    for (int r=0;r<4;r++){
      float v = fmaxf(fmaxf(s[0][r],s[1][r]), fmaxf(s[2][r],s[3][r]));
      v = fmaxf(v, __shfl_xor(v,1,16));
      v = fmaxf(v, __shfl_xor(v,2,16));
      v = fmaxf(v, __shfl_xor(v,4,16));
      v = fmaxf(v, __shfl_xor(v,8,16));
      float mn = fmaxf(mrow[r], v);
      bool dead = (mn == -INFINITY);      // fully-masked so far -> output 0 (NaN->0 semantics)
      float a = dead ? 1.f : __expf(mrow[r]-mn);
      float rsum = 0.f;
      for (int ct=0;ct<4;ct++){
        float p = dead ? 0.f : __expf(s[ct][r]-mn);
        s[ct][r]=p; rsum += p;
      }
      rsum += __shfl_xor(rsum,1,16);
      rsum += __shfl_xor(rsum,2,16);
      rsum += __shfl_xor(rsum,4,16);
      rsum += __shfl_xor(rsum,8,16);
      lrow[r] = lrow[r]*a + rsum;
      mrow[r] = mn;
      al[r] = a;
    }

    for (int d=0;d<8;d++)
      for (int r=0;r<4;r++)
        acc[d][r] *= al[r];

    // P: C-layout -> LDS (per-wave private strip; in-wave lgkmcnt ordering suffices)
    for (int ct=0;ct<4;ct++){
      int col = ct*16+lm;
      for (int r=0;r<4;r++)
        pw[(4*g+r)*72 + col] = f2b(s[ct][r]);
    }
    bf16x8 pa0 = *reinterpret_cast<const bf16x8*>(&pw[lm*72 + g*8]);
    bf16x8 pa1 = *reinterpret_cast<const bf16x8*>(&pw[lm*72 + 32 + g*8]);

    // O += P V  (B-frag from padded Vt: key contiguous at fixed d)
    for (int d=0;d<8;d++){
      bf16x8 v0 = *reinterpret_cast<const bf16x8*>(&ldsV[(d*16+lm)*VP + g*8]);
      acc[d] = __builtin_amdgcn_mfma_f32_16x16x32_bf16(pa0, v0, acc[d], 0,0,0);
      bf16x8 v1 = *reinterpret_cast<const bf16x8*>(&ldsV[(d*16+lm)*VP + 32 + g*8]);
      acc[d] = __builtin_amdgcn_mfma_f32_16x16x32_bf16(pa1, v1, acc[d], 0,0,0);
    }
  }

  float* Ob = attn + (size_t)b*SN*SD;
  int rbase = q0 + w*16 + 4*g;
  for (int r=0;r<4;r++){
    float inv = (lrow[r] > 0.f) ? (1.f/lrow[r]) : 0.f;
    for (int d=0;d<8;d++)
      Ob[(size_t)(rbase+r)*SD + d*16+lm] = acc[d][r]*inv;
  }
}

// ---- final projection: fp32 attn (16 rows) @ Wt + bo -> fp32 out, d-split ----
__global__ __launch_bounds__(256) void oproj_kernel(
    const float* __restrict__ X, const unsigned short* __restrict__ Wt,
    const float* __restrict__ bias, float* __restrict__ out)
{
  int tid = threadIdx.x;
  int w = tid>>6, ln = tid&63, g = ln>>4, lm = ln&15;
  int r0 = blockIdx.x*16;
  const float* xr = X + (size_t)(r0 + lm)*SD;
  bf16x8 af[4];
  for (int ks=0;ks<4;ks++){
    float4 x0 = *reinterpret_cast<const float4*>(xr + ks*32 + g*8);
    float4 x1 = *reinterpret_cast<const float4*>(xr + ks*32 + g*8 + 4);
    union { bf16x8 v; unsigned short s[8]; } u;
    u.s[0]=f2b(x0.x); u.s[1]=f2b(x0.y); u.s[2]=f2b(x0.z); u.s[3]=f2b(x0.w);
    u.s[4]=f2b(x1.x); u.s[5]=f2b(x1.y); u.s[6]=f2b(x1.z); u.s[7]=f2b(x1.w);
    af[ks]=u.v;
  }
  for (int dg=0; dg<2; dg++){
    int d = w*2 + dg;
    f32x4 acc = {0.f,0.f,0.f,0.f};
    for (int ks=0;ks<4;ks++){
      bf16x8 wf = *reinterpret_cast<const bf16x8*>(Wt + (d*16+lm)*SD + ks*32 + g*8);
      acc = __builtin_amdgcn_mfma_f32_16x16x32_bf16(af[ks], wf, acc, 0,0,0);
    }
    float bv = bias[d*16+lm];
    for (int r=0;r<4;r++)
      out[(size_t)(r0+4*g+r)*SD + d*16 + lm] = acc[r]+bv;
  }
}

extern "C" void kernel_launch(void* const* d_in, const int* in_sizes, int n_in,
                              void* d_out, int out_size, void* d_ws, size_t ws_size,
                              hipStream_t stream)
{
  const float* query = (const float*)d_in[0];
  const float* key   = (const float*)d_in[1];
  const int*   mask  = (const int*)d_in[2];
  const float* Wq = (const float*)d_in[3];
  const float* bq = (const float*)d_in[4];
  const float* Wk = (const float*)d_in[5];
  const float* bk = (const float*)d_in[6];
  const float* Wv = (const float*)d_in[7];
  const float* bv = (const float*)d_in[8];
  const float* Wo = (const float*)d_in[9];
  const float* bo = (const float*)d_in[10];
  float* out = (float*)d_out;

  // workspace layout (~40.1 MB total)
  unsigned short* qb = (unsigned short*)d_ws;        // bf16 q (pre-scaled by 1/sqrt(D))
  unsigned short* kb = qb + SZ;                      // bf16 k, row-major
  unsigned short* vt = kb + SZ;                      // bf16 v transposed [b][d][n]
  float* attn        = (float*)(vt + SZ);            // fp32 attention output
  unsigned short* wts = (unsigned short*)(attn + SZ);// 4x transposed bf16 weights

  const float sc = 0.08838834764831845f;  // 1/sqrt(128)

  prep_w_kernel<<<64,256,0,stream>>>(Wq,Wk,Wv,Wo,wts);
  proj_kernel  <<<2048,256,0,stream>>>(query, wts,        bq, sc,  qb);
  proj_kernel  <<<2048,256,0,stream>>>(key,   wts+16384,  bk, 1.f, kb);
  vproj_kernel <<<512,256,0,stream>>>(kb,    wts+32768,  bv, vt);
  flash_kernel <<<512,256,0,stream>>>(qb, kb, vt, mask, attn);
  oproj_kernel <<<2048,256,0,stream>>>(attn,  wts+49152,  bo, out);
}

// Round 5
// 490.743 us; speedup vs baseline: 1.4678x; 1.3505x over previous
//
#include <hip/hip_runtime.h>

#define SB 16
#define SN 2048
#define SD 128
#define NM 2049
#define SZ (SB*SN*SD)   // elements per (B,N,D) tensor

typedef __bf16 bf16x8 __attribute__((ext_vector_type(8)));
typedef float f32x4 __attribute__((ext_vector_type(4)));

// float -> bf16 round-to-nearest-even (inputs are finite)
__device__ __forceinline__ unsigned short f2b(float f){
  union { float f; unsigned int u; } v; v.f = f;
  unsigned int r = v.u + 0x7fffu + ((v.u >> 16) & 1u);
  return (unsigned short)(r >> 16);
}

__device__ __forceinline__ void async16(const void* g, void* l){
  __builtin_amdgcn_global_load_lds(
      (__attribute__((address_space(1))) void*)(g),
      (__attribute__((address_space(3))) void*)(l), 16, 0, 0);
}

// ---- transpose + cvt the 4 weight matrices: Wt[n*128+k] = bf16(W[k*128+n]) ----
__global__ __launch_bounds__(256) void prep_w_kernel(
    const float* __restrict__ Wq, const float* __restrict__ Wk,
    const float* __restrict__ Wv, const float* __restrict__ Wo,
    unsigned short* __restrict__ out)
{
  int widx = blockIdx.x >> 4;
  int kg   = blockIdx.x & 15;
  const float* W = (widx==0)?Wq:(widx==1)?Wk:(widx==2)?Wv:Wo;
  unsigned short* O = out + widx*16384;
  int t = threadIdx.x;
  int k = kg*8 + (t>>5);
  int n = (t&31)*4;
  float4 v = *reinterpret_cast<const float4*>(W + k*SD + n);
  O[(n+0)*SD + k] = f2b(v.x);
  O[(n+1)*SD + k] = f2b(v.y);
  O[(n+2)*SD + k] = f2b(v.z);
  O[(n+3)*SD + k] = f2b(v.w);
}

// ---- fused q/k/v projections. grid 1024: block = 32 query rows + 32 key rows.
// waves 0,1: q = query@Wq+bq (pre-scaled by 1/sqrt(D)) -> qb
// waves 2,3: k = key@Wk+bk -> kb, then v = k@Wv+bv -> vt (transposed [b][d][n])
__global__ __launch_bounds__(256,4) void qkv_kernel(
    const float* __restrict__ query, const float* __restrict__ key,
    const unsigned short* __restrict__ wts,
    const float* __restrict__ bq, const float* __restrict__ bk,
    const float* __restrict__ bv,
    unsigned short* __restrict__ qb, unsigned short* __restrict__ kb,
    unsigned short* __restrict__ vt)
{
  __shared__ unsigned short kstrip[2][16*136];  // per-k-wave A-frag strip
  __shared__ unsigned short vT[SD*40];          // [d][n-local 32], stride 40

  int tid=threadIdx.x;
  int w=tid>>6, ln=tid&63, g=ln>>4, lm=ln&15;
  int b = blockIdx.x >> 6, nt = blockIdx.x & 63;
  int n0 = nt*32;
  size_t rowbase = (size_t)b*SN + n0;
  const float sc = 0.08838834764831845f;  // 1/sqrt(128)

  const unsigned short* WqT = wts;
  const unsigned short* WkT = wts + 16384;
  const unsigned short* WvT = wts + 32768;

  if (w < 2){
    const float* xr = query + (rowbase + w*16 + lm)*SD;
    bf16x8 af[4];
    for (int ks=0;ks<4;ks++){
      float4 x0 = *reinterpret_cast<const float4*>(xr + ks*32 + g*8);
      float4 x1 = *reinterpret_cast<const float4*>(xr + ks*32 + g*8 + 4);
      union { bf16x8 v; unsigned short s[8]; } u;
      u.s[0]=f2b(x0.x); u.s[1]=f2b(x0.y); u.s[2]=f2b(x0.z); u.s[3]=f2b(x0.w);
      u.s[4]=f2b(x1.x); u.s[5]=f2b(x1.y); u.s[6]=f2b(x1.z); u.s[7]=f2b(x1.w);
      af[ks]=u.v;
    }
    for (int d=0; d<8; d++){
      f32x4 acc = {0.f,0.f,0.f,0.f};
      for (int ks=0;ks<4;ks++){
        bf16x8 wf = *reinterpret_cast<const bf16x8*>(WqT + (d*16+lm)*SD + ks*32 + g*8);
        acc = __builtin_amdgcn_mfma_f32_16x16x32_bf16(af[ks], wf, acc, 0,0,0);
      }
      float bb = bq[d*16+lm];
      for (int r=0;r<4;r++)
        qb[(rowbase + w*16 + 4*g + r)*SD + d*16 + lm] = f2b((acc[r]+bb)*sc);
    }
  } else {
    int wv = w-2;
    const float* xr = key + (rowbase + wv*16 + lm)*SD;
    bf16x8 af[4];
    for (int ks=0;ks<4;ks++){
      float4 x0 = *reinterpret_cast<const float4*>(xr + ks*32 + g*8);
      float4 x1 = *reinterpret_cast<const float4*>(xr + ks*32 + g*8 + 4);
      union { bf16x8 v; unsigned short s[8]; } u;
      u.s[0]=f2b(x0.x); u.s[1]=f2b(x0.y); u.s[2]=f2b(x0.z); u.s[3]=f2b(x0.w);
      u.s[4]=f2b(x1.x); u.s[5]=f2b(x1.y); u.s[6]=f2b(x1.z); u.s[7]=f2b(x1.w);
      af[ks]=u.v;
    }
    unsigned short* ks_ = kstrip[wv];
    for (int d=0; d<8; d++){
      f32x4 acc = {0.f,0.f,0.f,0.f};
      for (int ks=0;ks<4;ks++){
        bf16x8 wf = *reinterpret_cast<const bf16x8*>(WkT + (d*16+lm)*SD + ks*32 + g*8);
        acc = __builtin_amdgcn_mfma_f32_16x16x32_bf16(af[ks], wf, acc, 0,0,0);
      }
      float bb = bk[d*16+lm];
      for (int r=0;r<4;r++){
        unsigned short kv = f2b(acc[r]+bb);
        kb[(rowbase + wv*16 + 4*g + r)*SD + d*16 + lm] = kv;
        ks_[(4*g+r)*136 + d*16 + lm] = kv;
      }
    }
    // reload k as A-frags (per-wave private strip; in-wave lgkmcnt ordering)
    bf16x8 ka[4];
    for (int ks=0;ks<4;ks++)
      ka[ks] = *reinterpret_cast<const bf16x8*>(&ks_[lm*136 + ks*32 + g*8]);
    // v = k @ Wv + bv -> vT (transposed in LDS)
    for (int d=0; d<8; d++){
      f32x4 acc = {0.f,0.f,0.f,0.f};
      for (int ks=0;ks<4;ks++){
        bf16x8 wf = *reinterpret_cast<const bf16x8*>(WvT + (d*16+lm)*SD + ks*32 + g*8);
        acc = __builtin_amdgcn_mfma_f32_16x16x32_bf16(ka[ks], wf, acc, 0,0,0);
      }
      float bb = bv[d*16+lm];
      ushort4 pk;
      pk.x=f2b(acc[0]+bb); pk.y=f2b(acc[1]+bb);
      pk.z=f2b(acc[2]+bb); pk.w=f2b(acc[3]+bb);
      *reinterpret_cast<ushort4*>(&vT[(d*16+lm)*40 + wv*16 + 4*g]) = pk;
    }
  }
  __syncthreads();
  // write vt[b][d][n0..n0+31], coalesced
  int d = tid>>1, half = tid&1;
  const uint4* src = reinterpret_cast<const uint4*>(&vT[d*40 + half*16]);
  uint4* dst = reinterpret_cast<uint4*>(vt + (size_t)b*SD*SN + (size_t)d*SN + n0 + half*16);
  dst[0]=src[0]; dst[1]=src[1];
}

// ---- flash attention + fused output projection ----
// DMA double-buffered K/V with XOR-swizzled LDS layout (conflict-free b128 reads,
// no staging VGPRs). Mask register-prefetched one tile ahead. Epilogue: out = O@Wo+bo.
__global__ __launch_bounds__(256,4) void flash_kernel(
    const unsigned short* __restrict__ qb, const unsigned short* __restrict__ kb,
    const unsigned short* __restrict__ vt, const int* __restrict__ mask,
    const unsigned short* __restrict__ WoT, const float* __restrict__ bo,
    float* __restrict__ out)
{
  __shared__ unsigned short bufK[2][64*128];   // [key][d], chunk-swizzled
  __shared__ unsigned short bufV[2][128*64];   // [d][key], chunk-swizzled
  __shared__ unsigned short ldsP[4*16*72];     // per-wave P strip

  int tid=threadIdx.x;
  int w=tid>>6, ln=tid&63, g=ln>>4, lm=ln&15;
  int b = blockIdx.x >> 5, qt = blockIdx.x & 31;
  int q0 = qt*64;

  const unsigned short* Qb = qb + (size_t)b*SN*SD;
  const unsigned short* Kb = kb + (size_t)b*SN*SD;
  const unsigned short* Vb = vt + (size_t)b*SD*SN;
  const int* Mb = mask + (size_t)b*NM*NM;

  // DMA issue: thread handles chunks p = c*256+tid; LDS phys chunk p,
  // global logical chunk = phys ^ (row & rowmask).
  auto issueK = [&](int k0, int bi){
    const char* gbase = (const char*)Kb + (size_t)k0*256;
    for (int c=0;c<4;c++){
      int p = c*256 + tid;
      int row = p>>4, lc = (p&15) ^ (row&15);
      async16(gbase + (size_t)row*256 + lc*16, (char*)bufK[bi] + p*16);
    }
  };
  auto issueV = [&](int k0, int bi){
    const char* gbase = (const char*)Vb + (size_t)k0*2;
    for (int c=0;c<4;c++){
      int p = c*256 + tid;
      int row = p>>3, lc = (p&7) ^ (row&7);
      async16(gbase + (size_t)row*4096 + lc*16, (char*)bufV[bi] + p*16);
    }
  };

  issueK(0,0); issueV(0,0);

  bf16x8 qf[4];
  {
    const unsigned short* qr = Qb + (size_t)(q0 + w*16 + lm)*SD;
    for (int ks=0;ks<4;ks++)
      qf[ks] = *reinterpret_cast<const bf16x8*>(qr + ks*32 + g*8);
  }

  int qr1 = 1 + q0 + w*16 + 4*g;
  const int* mbase = Mb + (size_t)qr1*NM + 1 + lm;
  int mreg[16];
  for (int ct=0;ct<4;ct++)
    for (int r=0;r<4;r++)
      mreg[ct*4+r] = mbase[(size_t)r*NM + ct*16];

  float mrow[4], lrow[4], al[4];
  f32x4 acc[8];
  for (int r=0;r<4;r++){ mrow[r]=-INFINITY; lrow[r]=0.f; }
  for (int d=0;d<8;d++){ f32x4 z={0.f,0.f,0.f,0.f}; acc[d]=z; }
  unsigned short* pw = &ldsP[w*16*72];

  for (int kt=0; kt<32; kt++){
    __syncthreads();          // DMA for buf[kt&1] drained; all done reading buf[(kt+1)&1]
    int cur = kt&1;
    if (kt<31){ issueK((kt+1)*64, cur^1); issueV((kt+1)*64, cur^1); }

    // ---- S = Q K^T (wave strip: 16 q-rows x 64 keys), swizzled reads ----
    f32x4 s[4];
    for (int ct=0;ct<4;ct++){
      f32x4 z = {0.f,0.f,0.f,0.f};
      for (int ks=0;ks<4;ks++){
        bf16x8 kf = *reinterpret_cast<const bf16x8*>(
            &bufK[cur][(ct*16+lm)*128 + (((ks*4+g)^lm))*8]);
        z = __builtin_amdgcn_mfma_f32_16x16x32_bf16(qf[ks], kf, z, 0,0,0);
      }
      s[ct]=z;
    }

    // apply inverted mask, then prefetch next tile's mask
    for (int ct=0;ct<4;ct++)
      for (int r=0;r<4;r++)
        s[ct][r] = mreg[ct*4+r] ? -INFINITY : s[ct][r];
    if (kt<31){
      const int* mp = mbase + (kt+1)*64;
      for (int ct=0;ct<4;ct++)
        for (int r=0;r<4;r++)
          mreg[ct*4+r] = mp[(size_t)r*NM + ct*16];
    }

    // ---- online softmax ----
    for (int r=0;r<4;r++){
      float v = fmaxf(fmaxf(s[0][r],s[1][r]), fmaxf(s[2][r],s[3][r]));
      v = fmaxf(v, __shfl_xor(v,1,16));
      v = fmaxf(v, __shfl_xor(v,2,16));
      v = fmaxf(v, __shfl_xor(v,4,16));
      v = fmaxf(v, __shfl_xor(v,8,16));
      float mn = fmaxf(mrow[r], v);
      bool dead = (mn == -INFINITY);    // fully-masked so far -> zeros (NaN->0 semantics)
      float a = dead ? 1.f : __expf(mrow[r]-mn);
      float rsum = 0.f;
      for (int ct=0;ct<4;ct++){
        float p = dead ? 0.f : __expf(s[ct][r]-mn);
        s[ct][r]=p; rsum += p;
      }
      rsum += __shfl_xor(rsum,1,16);
      rsum += __shfl_xor(rsum,2,16);
      rsum += __shfl_xor(rsum,4,16);
      rsum += __shfl_xor(rsum,8,16);
      lrow[r] = lrow[r]*a + rsum;
      mrow[r] = mn;
      al[r] = a;
    }
    for (int d=0;d<8;d++)
      for (int r=0;r<4;r++)
        acc[d][r] *= al[r];

    // P: C-layout -> per-wave LDS strip -> A-frags
    for (int ct=0;ct<4;ct++){
      int col = ct*16+lm;
      for (int r=0;r<4;r++)
        pw[(4*g+r)*72 + col] = f2b(s[ct][r]);
    }
    bf16x8 pa0 = *reinterpret_cast<const bf16x8*>(&pw[lm*72 + g*8]);
    bf16x8 pa1 = *reinterpret_cast<const bf16x8*>(&pw[lm*72 + 32 + g*8]);

    // O += P V (swizzled V reads)
    for (int d=0;d<8;d++){
      bf16x8 v0 = *reinterpret_cast<const bf16x8*>(
          &bufV[cur][(d*16+lm)*64 + ((g^(lm&7)))*8]);
      acc[d] = __builtin_amdgcn_mfma_f32_16x16x32_bf16(pa0, v0, acc[d], 0,0,0);
      bf16x8 v1 = *reinterpret_cast<const bf16x8*>(
          &bufV[cur][(d*16+lm)*64 + (((4+g)^(lm&7)))*8]);
      acc[d] = __builtin_amdgcn_mfma_f32_16x16x32_bf16(pa1, v1, acc[d], 0,0,0);
    }
  }

  // ---- epilogue: out = (O/l) @ Wo + bo ----
  __syncthreads();            // done with bufK/bufV; reuse as bf16 A-frag strips
  float inv[4];
  for (int r=0;r<4;r++) inv[r] = (lrow[r] > 0.f) ? (1.f/lrow[r]) : 0.f;
  unsigned short* strip = &bufK[0][0] + w*2176;   // 16 rows x 136 stride
  for (int d=0;d<8;d++)
    for (int r=0;r<4;r++)
      strip[(4*g+r)*136 + d*16 + lm] = f2b(acc[d][r]*inv[r]);
  bf16x8 oa[4];
  for (int ks=0;ks<4;ks++)
    oa[ks] = *reinterpret_cast<const bf16x8*>(&strip[lm*136 + ks*32 + g*8]);
  float* Ob = out + ((size_t)b*SN + q0 + w*16)*SD;
  for (int dc=0; dc<8; dc++){
    f32x4 o = {0.f,0.f,0.f,0.f};
    for (int ks=0;ks<4;ks++){
      bf16x8 wf = *reinterpret_cast<const bf16x8*>(WoT + (dc*16+lm)*SD + ks*32 + g*8);
      o = __builtin_amdgcn_mfma_f32_16x16x32_bf16(oa[ks], wf, o, 0,0,0);
    }
    float bb = bo[dc*16+lm];
    for (int r=0;r<4;r++)
      Ob[(size_t)(4*g+r)*SD + dc*16 + lm] = o[r]+bb;
  }
}

extern "C" void kernel_launch(void* const* d_in, const int* in_sizes, int n_in,
                              void* d_out, int out_size, void* d_ws, size_t ws_size,
                              hipStream_t stream)
{
  const float* query = (const float*)d_in[0];
  const float* key   = (const float*)d_in[1];
  const int*   mask  = (const int*)d_in[2];
  const float* Wq = (const float*)d_in[3];
  const float* bq = (const float*)d_in[4];
  const float* Wk = (const float*)d_in[5];
  const float* bk = (const float*)d_in[6];
  const float* Wv = (const float*)d_in[7];
  const float* bv = (const float*)d_in[8];
  const float* Wo = (const float*)d_in[9];
  const float* bo = (const float*)d_in[10];
  float* out = (float*)d_out;

  // workspace: qb, kb, vt (bf16) + transposed weights
  unsigned short* qb = (unsigned short*)d_ws;
  unsigned short* kb = qb + SZ;
  unsigned short* vt = kb + SZ;
  unsigned short* wts = vt + SZ;   // 4 x 16384 ushorts

  prep_w_kernel<<<64,256,0,stream>>>(Wq,Wk,Wv,Wo,wts);
  qkv_kernel  <<<1024,256,0,stream>>>(query, key, wts, bq, bk, bv, qb, kb, vt);
  flash_kernel<<<512,256,0,stream>>>(qb, kb, vt, mask, wts+49152, bo, out);
}